// Round 1
// baseline (132.084 us; speedup 1.0000x reference)
//
#include <hip/hip_runtime.h>

#define NUM_CLASSES 64

// One fused pass over predictions + targets.
// Layout: 16 lanes per row, each lane owns 4 consecutive columns (one float4).
// Wave of 64 lanes covers 4 contiguous rows -> 1KB contiguous per wave load.
__global__ __launch_bounds__(256) void loss_pass1(
    const float* __restrict__ pred,      // [n][64]
    const int* __restrict__ tgt,         // [n]
    float* __restrict__ g_colsum,        // [64]  (pre-zeroed)
    unsigned int* __restrict__ g_cnt,    // [64]  (pre-zeroed)
    float* __restrict__ g_nll,           // [1]   (pre-zeroed)  sum of picked log-probs
    int n)
{
    __shared__ float s_col[NUM_CLASSES];
    __shared__ unsigned int s_cnt[NUM_CLASSES];
    __shared__ float s_nll[4];  // one per wave (256 threads = 4 waves)

    const int t = threadIdx.x;
    if (t < NUM_CLASSES) { s_col[t] = 0.0f; s_cnt[t] = 0u; }
    __syncthreads();

    const int c16  = t & 15;          // which float4 within the row
    const int rloc = t >> 4;          // row within this block's 16-row slab
    const int c0   = c16 * 4;         // first column this lane owns
    const int rows_per_iter = (blockDim.x >> 4) * gridDim.x;

    float ca0 = 0.f, ca1 = 0.f, ca2 = 0.f, ca3 = 0.f;  // per-column exp sums
    float nllacc = 0.f;                                 // picked log-prob sum

    for (int row = blockIdx.x * (blockDim.x >> 4) + rloc; row < n; row += rows_per_iter) {
        const float4 v = *reinterpret_cast<const float4*>(pred + (size_t)row * NUM_CLASSES + c0);
        ca0 += __expf(v.x);
        ca1 += __expf(v.y);
        ca2 += __expf(v.z);
        ca3 += __expf(v.w);

        const int tg = tgt[row];                 // L1 broadcast across the 16 lanes
        if (c16 == 0) atomicAdd(&s_cnt[tg], 1u); // histogram: one atomic per row
        const int d = tg - c0;
        if ((unsigned)d < 4u) {                  // my columns contain the target
            nllacc += (d == 0) ? v.x : (d == 1) ? v.y : (d == 2) ? v.z : v.w;
        }
    }

    // column partials -> LDS (4 atomics per thread, once)
    atomicAdd(&s_col[c0 + 0], ca0);
    atomicAdd(&s_col[c0 + 1], ca1);
    atomicAdd(&s_col[c0 + 2], ca2);
    atomicAdd(&s_col[c0 + 3], ca3);

    // nll: butterfly within wave, then one LDS slot per wave
    for (int off = 32; off; off >>= 1) nllacc += __shfl_down(nllacc, off);
    if ((t & 63) == 0) s_nll[t >> 6] = nllacc;
    __syncthreads();  // also orders the s_col/s_cnt atomics above

    if (t == 0) atomicAdd(g_nll, s_nll[0] + s_nll[1] + s_nll[2] + s_nll[3]);
    if (t < NUM_CLASSES) {
        atomicAdd(&g_colsum[t], s_col[t]);
        atomicAdd(&g_cnt[t], s_cnt[t]);
    }
}

__global__ void loss_finalize(const float* __restrict__ g_colsum,
                              const unsigned int* __restrict__ g_cnt,
                              const float* __restrict__ g_nll,
                              float* __restrict__ out, int n)
{
    const int t = threadIdx.x;  // 64 threads, one wave
    const float diff = (float)g_cnt[t] - g_colsum[t];
    float p = diff * diff;
    for (int off = 32; off; off >>= 1) p += __shfl_down(p, off);
    if (t == 0) out[0] = (p - g_nll[0]) / (float)n;  // penalty/n + (-sum/n)
}

extern "C" void kernel_launch(void* const* d_in, const int* in_sizes, int n_in,
                              void* d_out, int out_size, void* d_ws, size_t ws_size,
                              hipStream_t stream)
{
    const float* pred = (const float*)d_in[0];
    const int* tgt    = (const int*)d_in[1];
    const int n       = in_sizes[1];  // 2,000,000 rows

    float*        g_colsum = (float*)d_ws;
    unsigned int* g_cnt    = (unsigned int*)((char*)d_ws + 256);
    float*        g_nll    = (float*)((char*)d_ws + 512);

    hipMemsetAsync(d_ws, 0, 1024, stream);  // accumulators must start at 0 every call

    loss_pass1<<<2048, 256, 0, stream>>>(pred, tgt, g_colsum, g_cnt, g_nll, n);
    loss_finalize<<<1, 64, 0, stream>>>(g_colsum, g_cnt, g_nll, (float*)d_out, n);
}

// Round 2
// 104.636 us; speedup vs baseline: 1.2623x; 1.2623x over previous
//
#include <hip/hip_runtime.h>

#define NUM_CLASSES 64
#define UNROLL 4          // rows per thread per main-loop iteration
#define SLAB 16           // row-groups per block (blockDim/16)

typedef float f32x4 __attribute__((ext_vector_type(4)));

// Fused pass: per-class exp column sums + target histogram + NLL pick.
// 16 lanes per row, each lane owns 4 consecutive columns (one float4).
// UNROLL=4 independent row loads in flight per thread to cover HBM latency.
__global__ __launch_bounds__(256) void loss_pass1(
    const float* __restrict__ pred,      // [n][64]
    const int* __restrict__ tgt,         // [n]
    float* __restrict__ g_colsum,        // [64]  (pre-zeroed)
    unsigned int* __restrict__ g_cnt,    // [64]  (pre-zeroed)
    float* __restrict__ g_nll,           // [1]   (pre-zeroed)
    int n)
{
    __shared__ float s_col[NUM_CLASSES];
    __shared__ unsigned int s_cnt[NUM_CLASSES];
    __shared__ float s_nll[4];

    const int t = threadIdx.x;
    if (t < NUM_CLASSES) { s_col[t] = 0.0f; s_cnt[t] = 0u; }
    __syncthreads();

    const int c16  = t & 15;           // which float4 within the row
    const int rloc = t >> 4;           // row-group within block
    const int c0   = c16 * 4;          // first column this lane owns
    const int rows_per_block = SLAB * UNROLL;                 // 64
    const long stride = (long)rows_per_block * gridDim.x;

    float ca0 = 0.f, ca1 = 0.f, ca2 = 0.f, ca3 = 0.f;
    float nllacc = 0.f;

    for (long base = (long)blockIdx.x * rows_per_block; base < n; base += stride) {
        f32x4 v[UNROLL];
        int   tg[UNROLL];

        if (base + rows_per_block <= n) {
            // fast path: all rows valid — issue all loads first (ILP)
            #pragma unroll
            for (int j = 0; j < UNROLL; ++j) {
                const long row = base + rloc + j * SLAB;
                v[j]  = __builtin_nontemporal_load(
                          reinterpret_cast<const f32x4*>(pred + row * NUM_CLASSES + c0));
                tg[j] = tgt[row];
            }
            #pragma unroll
            for (int j = 0; j < UNROLL; ++j) {
                ca0 += __expf(v[j][0]);
                ca1 += __expf(v[j][1]);
                ca2 += __expf(v[j][2]);
                ca3 += __expf(v[j][3]);
                if (c16 == j) atomicAdd(&s_cnt[tg[j]], 1u);   // spread hist atomics
                const int d = tg[j] - c0;
                if ((unsigned)d < 4u) nllacc += v[j][d];
            }
        } else {
            // tail (never taken for n % 64 == 0, kept for correctness)
            #pragma unroll
            for (int j = 0; j < UNROLL; ++j) {
                const long row = base + rloc + j * SLAB;
                if (row >= n) continue;
                const f32x4 w = *reinterpret_cast<const f32x4*>(pred + row * NUM_CLASSES + c0);
                const int g = tgt[row];
                ca0 += __expf(w[0]);
                ca1 += __expf(w[1]);
                ca2 += __expf(w[2]);
                ca3 += __expf(w[3]);
                if (c16 == j) atomicAdd(&s_cnt[g], 1u);
                const int d = g - c0;
                if ((unsigned)d < 4u) nllacc += w[d];
            }
        }
    }

    atomicAdd(&s_col[c0 + 0], ca0);
    atomicAdd(&s_col[c0 + 1], ca1);
    atomicAdd(&s_col[c0 + 2], ca2);
    atomicAdd(&s_col[c0 + 3], ca3);

    for (int off = 32; off; off >>= 1) nllacc += __shfl_down(nllacc, off);
    if ((t & 63) == 0) s_nll[t >> 6] = nllacc;
    __syncthreads();

    if (t == 0) atomicAdd(g_nll, s_nll[0] + s_nll[1] + s_nll[2] + s_nll[3]);
    if (t < NUM_CLASSES) {
        atomicAdd(&g_colsum[t], s_col[t]);
        atomicAdd(&g_cnt[t], s_cnt[t]);
    }
}

__global__ void loss_finalize(const float* __restrict__ g_colsum,
                              const unsigned int* __restrict__ g_cnt,
                              const float* __restrict__ g_nll,
                              float* __restrict__ out, int n)
{
    const int t = threadIdx.x;  // 64 threads
    const float diff = (float)g_cnt[t] - g_colsum[t];
    float p = diff * diff;
    for (int off = 32; off; off >>= 1) p += __shfl_down(p, off);
    if (t == 0) out[0] = (p - g_nll[0]) / (float)n;
}

extern "C" void kernel_launch(void* const* d_in, const int* in_sizes, int n_in,
                              void* d_out, int out_size, void* d_ws, size_t ws_size,
                              hipStream_t stream)
{
    const float* pred = (const float*)d_in[0];
    const int* tgt    = (const int*)d_in[1];
    const int n       = in_sizes[1];

    float*        g_colsum = (float*)d_ws;
    unsigned int* g_cnt    = (unsigned int*)((char*)d_ws + 256);
    float*        g_nll    = (float*)((char*)d_ws + 512);

    hipMemsetAsync(d_ws, 0, 1024, stream);

    loss_pass1<<<2048, 256, 0, stream>>>(pred, tgt, g_colsum, g_cnt, g_nll, n);
    loss_finalize<<<1, 64, 0, stream>>>(g_colsum, g_cnt, g_nll, (float*)d_out, n);
}